// Round 10
// baseline (98.371 us; speedup 1.0000x reference)
//
#include <hip/hip_runtime.h>
#include <cstdint>

#define NN 4096
#define FF 512

typedef short bf16x8 __attribute__((ext_vector_type(8)));
typedef float f32x4 __attribute__((ext_vector_type(4)));
typedef float f32x16 __attribute__((ext_vector_type(16)));

__device__ __forceinline__ uint16_t f2bf(float f) {
    uint32_t u = __builtin_bit_cast(uint32_t, f);
    u += 0x7FFFu + ((u >> 16) & 1u);   // round-to-nearest-even
    return (uint16_t)(u >> 16);
}
__device__ __forceinline__ float bf2f(uint32_t h) {
    uint32_t u = h << 16;
    return __builtin_bit_cast(float, u);
}

// ---------------------------------------------------------------------------
// k_prep: Abf[i][j] = bf16(adj[i][j] + (i==j)), d_i = rsqrt(1 + rowsum(adj))
// ---------------------------------------------------------------------------
__global__ __launch_bounds__(256) void k_prep(const float* __restrict__ adj,
                                              float* __restrict__ d,
                                              uint16_t* __restrict__ Abf) {
    const int row  = blockIdx.x * 4 + (threadIdx.x >> 6);
    const int lane = threadIdx.x & 63;
    const float4* p = (const float4*)(adj + (size_t)row * NN);
    float4 v[16];
    float s = 0.f;
#pragma unroll
    for (int i = 0; i < 16; ++i) {
        v[i] = p[lane + i * 64];
        s += (v[i].x + v[i].y) + (v[i].z + v[i].w);
    }
#pragma unroll
    for (int off = 1; off < 64; off <<= 1) s += __shfl_xor(s, off);
    const float di = rsqrtf(s + 1.0f);
    if (lane == 0) d[row] = di;
    uint16_t* outp = Abf + (size_t)row * NN;
#pragma unroll
    for (int i = 0; i < 16; ++i) {
        const int cb = (lane + i * 64) * 4;
        float a0 = v[i].x, a1 = v[i].y, a2 = v[i].z, a3 = v[i].w;
        if (cb + 0 == row) a0 += 1.0f;
        if (cb + 1 == row) a1 += 1.0f;
        if (cb + 2 == row) a2 += 1.0f;
        if (cb + 3 == row) a3 += 1.0f;
        ushort4 o;
        o.x = f2bf(a0); o.y = f2bf(a1); o.z = f2bf(a2); o.w = f2bf(a3);
        *(ushort4*)(outp + cb) = o;
    }
}

// ---------------------------------------------------------------------------
// k_xc / k_wc: f32 -> bf16 casts
// ---------------------------------------------------------------------------
__global__ __launch_bounds__(256) void k_xc(const float* __restrict__ x,
                                            uint16_t* __restrict__ xbf) {
    const size_t t4 = (size_t)blockIdx.x * 256 + threadIdx.x;
    float4 v = *(const float4*)(x + t4 * 4);
    ushort4 o;
    o.x = f2bf(v.x); o.y = f2bf(v.y); o.z = f2bf(v.z); o.w = f2bf(v.w);
    *(ushort4*)(xbf + t4 * 4) = o;
}

__global__ __launch_bounds__(256) void k_wc(const float* __restrict__ W,
                                            uint16_t* __restrict__ Wbf) {
    const size_t t4 = (size_t)blockIdx.x * 256 + threadIdx.x;
    float4 v = *(const float4*)(W + t4 * 4);
    ushort4 o;
    o.x = f2bf(v.x); o.y = f2bf(v.y); o.z = f2bf(v.z); o.w = f2bf(v.w);
    *(ushort4*)(Wbf + t4 * 4) = o;
}

// ---------------------------------------------------------------------------
// k_zt: zdT[n][k] = bf16(d[k] * z32[k][n])   (transpose+scale, via LDS)
// ---------------------------------------------------------------------------
__global__ __launch_bounds__(256) void k_zt(const float* __restrict__ z32,
                                            const float* __restrict__ d,
                                            uint16_t* __restrict__ zdT) {
    __shared__ uint16_t t[64][72];
    const int k0 = blockIdx.x * 64;
    const int n0 = blockIdx.y * 64;
    const int tid = threadIdx.x;
    const int r   = tid >> 4;
    const int c4  = tid & 15;
#pragma unroll
    for (int pass = 0; pass < 4; ++pass) {
        const int row = pass * 16 + r;
        float4 v = *(const float4*)(z32 + (size_t)(k0 + row) * FF + n0 + c4 * 4);
        const float dk = d[k0 + row];
        t[c4 * 4 + 0][row] = f2bf(v.x * dk);
        t[c4 * 4 + 1][row] = f2bf(v.y * dk);
        t[c4 * 4 + 2][row] = f2bf(v.z * dk);
        t[c4 * 4 + 3][row] = f2bf(v.w * dk);
    }
    __syncthreads();
#pragma unroll
    for (int pass = 0; pass < 2; ++pass) {
        const int cid = pass * 256 + tid;
        const int n  = cid >> 3;
        const int ch = cid & 7;
        *(uint4*)(zdT + (size_t)(n0 + n) * NN + k0 + ch * 8) = *(const uint4*)&t[n][ch * 8];
    }
}

// ---------------------------------------------------------------------------
// k_mm (small GEMM, R7-R9 verified): C = A[.][K] * Bt[.][K]^T, f32 out.
// ---------------------------------------------------------------------------
template <int BM, int BN, int K>
__global__ __launch_bounds__(256, 4) void k_mm(const uint16_t* __restrict__ A,
                                               const uint16_t* __restrict__ Bt,
                                               float* __restrict__ outp) {
    constexpr int NTC   = FF / BN;
    constexpr int NT    = K / 64;
    constexpr int MFR   = BM / 32;
    constexpr int NFR   = BN / 32;
    constexpr int LPT_A = BM / 32;
    constexpr int LPT_B = BN / 32;

    __shared__ uint16_t As[BM * 64];
    __shared__ uint16_t Bs[BN * 64];

    const int id   = blockIdx.x;
    const int mt   = id / NTC;
    const int nt   = id % NTC;
    const int m0 = mt * BM;
    const int n0 = nt * BN;

    const int tid  = threadIdx.x;
    const int w    = tid >> 6;
    const int lane = tid & 63;
    const int wm = w >> 1, wn = w & 1;

    f32x4 acc[MFR][NFR] = {};

    for (int t = 0; t < NT; ++t) {
        const int ktb = t * 64;
#pragma unroll
        for (int i = 0; i < LPT_A; ++i) {
            const int boff = i * 4096 + tid * 16;
            const int row  = boff >> 7;
            const int q    = (boff >> 4) & 7;
            const int c    = q ^ (row & 7);
            const uint16_t* src = A + (size_t)(m0 + row) * K + ktb + c * 8;
            __builtin_amdgcn_global_load_lds(
                (const __attribute__((address_space(1))) void*)src,
                (__attribute__((address_space(3))) void*)&As[boff >> 1],
                16, 0, 0);
        }
#pragma unroll
        for (int i = 0; i < LPT_B; ++i) {
            const int boff = i * 4096 + tid * 16;
            const int row  = boff >> 7;
            const int q    = (boff >> 4) & 7;
            const int c    = q ^ (row & 7);
            const uint16_t* src = Bt + (size_t)(n0 + row) * K + ktb + c * 8;
            __builtin_amdgcn_global_load_lds(
                (const __attribute__((address_space(1))) void*)src,
                (__attribute__((address_space(3))) void*)&Bs[boff >> 1],
                16, 0, 0);
        }
        __syncthreads();
#pragma unroll
        for (int kk = 0; kk < 2; ++kk) {
            const int cl = kk * 4 + (lane >> 4);
            bf16x8 af[MFR], bfr[NFR];
#pragma unroll
            for (int mf = 0; mf < MFR; ++mf) {
                const int r = wm * (MFR * 16) + mf * 16 + (lane & 15);
                af[mf] = *(const bf16x8*)&As[r * 64 + ((cl ^ (r & 7)) << 3)];
            }
#pragma unroll
            for (int nf = 0; nf < NFR; ++nf) {
                const int r = wn * (NFR * 16) + nf * 16 + (lane & 15);
                bfr[nf] = *(const bf16x8*)&Bs[r * 64 + ((cl ^ (r & 7)) << 3)];
            }
#pragma unroll
            for (int mf = 0; mf < MFR; ++mf)
#pragma unroll
                for (int nf = 0; nf < NFR; ++nf)
                    acc[mf][nf] = __builtin_amdgcn_mfma_f32_16x16x32_bf16(
                        af[mf], bfr[nf], acc[mf][nf], 0, 0, 0);
        }
        __syncthreads();
    }

    const int rbase = m0 + wm * (MFR * 16) + ((lane >> 4) << 2);
    const int cbase = n0 + wn * (NFR * 16) + (lane & 15);
#pragma unroll
    for (int mf = 0; mf < MFR; ++mf)
#pragma unroll
        for (int nf = 0; nf < NFR; ++nf) {
            const int col = cbase + nf * 16;
#pragma unroll
            for (int r = 0; r < 4; ++r) {
                const int row = rbase + mf * 16 + r;
                outp[(size_t)row * FF + col] = acc[mf][nf][r];
            }
        }
}

// ---------------------------------------------------------------------------
// k_mmx (big GEMM, R9 loop UNCHANGED; epilogue -> packed coalesced):
// parts tile layout: [bid 0..511][tid 0..255][64 bf16] — 128 B/thread stores.
// Launched TWICE this round (idempotent) so total-delta measures t_mmx exactly.
// ---------------------------------------------------------------------------
__global__ __launch_bounds__(256, 2) void k_mmx(const uint16_t* __restrict__ A,
                                                const uint16_t* __restrict__ Bt,
                                                uint16_t* __restrict__ parts) {
    constexpr int BM = 128, BN = 128, K = NN, SPLITK = 4;
    constexpr int NTC   = FF / BN;        // 4
    constexpr int KSLEN = K / SPLITK;     // 1024
    constexpr int NT    = KSLEN / 64;     // 16
    constexpr int MTX   = (NN / BM) / 8;  // 4

    __shared__ uint16_t As[2][BM * 64];
    __shared__ uint16_t Bs[2][BN * 64];

    const int id   = blockIdx.x;          // 0..511
    const int xcd  = id & 7;
    const int slot = id >> 3;             // 0..63
    const int mt   = xcd * MTX + slot / (NTC * SPLITK);
    const int rem  = slot % (NTC * SPLITK);
    const int nt   = rem % NTC;
    const int ks   = rem / NTC;
    const int m0 = mt * BM;
    const int n0 = nt * BN;
    const int k0 = ks * KSLEN;

    const int tid  = threadIdx.x;
    const int w    = tid >> 6;
    const int lane = tid & 63;
    const int wm = w >> 1, wn = w & 1;

    f32x16 acc[2][2] = {};

    auto STAGE = [&](int t, int buf) {
        const int ktb = k0 + t * 64;
#pragma unroll
        for (int i = 0; i < 4; ++i) {
            const int boff = i * 4096 + tid * 16;
            const int row  = boff >> 7;
            const int q    = (boff >> 4) & 7;
            const int c    = q ^ (row & 7);
            const uint16_t* src = A + (size_t)(m0 + row) * K + ktb + c * 8;
            __builtin_amdgcn_global_load_lds(
                (const __attribute__((address_space(1))) void*)src,
                (__attribute__((address_space(3))) void*)&As[buf][boff >> 1],
                16, 0, 0);
        }
#pragma unroll
        for (int i = 0; i < 4; ++i) {
            const int boff = i * 4096 + tid * 16;
            const int row  = boff >> 7;
            const int q    = (boff >> 4) & 7;
            const int c    = q ^ (row & 7);
            const uint16_t* src = Bt + (size_t)(n0 + row) * K + ktb + c * 8;
            __builtin_amdgcn_global_load_lds(
                (const __attribute__((address_space(1))) void*)src,
                (__attribute__((address_space(3))) void*)&Bs[buf][boff >> 1],
                16, 0, 0);
        }
    };

    auto COMPUTE = [&](int buf) {
#pragma unroll
        for (int kk = 0; kk < 4; ++kk) {
            const int cl = kk * 2 + (lane >> 5);
            bf16x8 af[2], bfr[2];
#pragma unroll
            for (int mf = 0; mf < 2; ++mf) {
                const int r = wm * 64 + mf * 32 + (lane & 31);
                af[mf] = *(const bf16x8*)&As[buf][r * 64 + ((cl ^ (r & 7)) << 3)];
            }
#pragma unroll
            for (int nf = 0; nf < 2; ++nf) {
                const int r = wn * 64 + nf * 32 + (lane & 31);
                bfr[nf] = *(const bf16x8*)&Bs[buf][r * 64 + ((cl ^ (r & 7)) << 3)];
            }
#pragma unroll
            for (int mf = 0; mf < 2; ++mf)
#pragma unroll
                for (int nf = 0; nf < 2; ++nf)
                    acc[mf][nf] = __builtin_amdgcn_mfma_f32_32x32x16_bf16(
                        af[mf], bfr[nf], acc[mf][nf], 0, 0, 0);
        }
    };

    STAGE(0, 0);
    for (int t = 0; t < NT - 1; ++t) {
        STAGE(t + 1, (t + 1) & 1);
        asm volatile("s_waitcnt vmcnt(8)" ::: "memory");
        __builtin_amdgcn_s_barrier();
        COMPUTE(t & 1);
        __builtin_amdgcn_s_barrier();
    }
    asm volatile("s_waitcnt vmcnt(0)" ::: "memory");
    __builtin_amdgcn_s_barrier();
    COMPUTE((NT - 1) & 1);

    // epilogue: packed per-tile layout, 128 B contiguous per thread.
    uint16_t* dst = parts + (size_t)id * (256 * 64) + (size_t)tid * 64;
#pragma unroll
    for (int mf = 0; mf < 2; ++mf)
#pragma unroll
        for (int nf = 0; nf < 2; ++nf) {
            uint32_t wbuf[8];
#pragma unroll
            for (int rp = 0; rp < 8; ++rp) {
                uint32_t lo = f2bf(acc[mf][nf][2 * rp]);
                uint32_t hi = f2bf(acc[mf][nf][2 * rp + 1]);
                wbuf[rp] = lo | (hi << 16);
            }
            uint4* o = (uint4*)(dst + (mf * 2 + nf) * 16);
            o[0] = *(uint4*)&wbuf[0];
            o[1] = *(uint4*)&wbuf[4];
        }
}

// ---------------------------------------------------------------------------
// k_red: inverse-map reduction over the packed-tile parts layout.
// block = one (mt,nt) 128x128 tile; thread reads its 4 x 128 B (ks planes),
// sums in p-order 0..3 (identical numerics to R9), scatters f32 out.
// ---------------------------------------------------------------------------
__global__ __launch_bounds__(256) void k_red(const uint16_t* __restrict__ parts,
                                             const float* __restrict__ d,
                                             const float* __restrict__ b,
                                             float* __restrict__ out) {
    const int mt  = blockIdx.x >> 2;     // 0..31
    const int nt  = blockIdx.x & 3;      // 0..3
    const int xcd = mt >> 2;
    const int mtl = mt & 3;
    const int tid = threadIdx.x;

    float s[64];
#pragma unroll
    for (int i = 0; i < 64; ++i) s[i] = 0.f;
#pragma unroll
    for (int ks = 0; ks < 4; ++ks) {
        const int bid = ((mtl * 16 + ks * 4 + nt) << 3) | xcd;
        const uint16_t* src = parts + (size_t)bid * (256 * 64) + (size_t)tid * 64;
#pragma unroll
        for (int i = 0; i < 8; ++i) {
            uint4 v = ((const uint4*)src)[i];
            s[i * 8 + 0] += bf2f(v.x & 0xFFFF); s[i * 8 + 1] += bf2f(v.x >> 16);
            s[i * 8 + 2] += bf2f(v.y & 0xFFFF); s[i * 8 + 3] += bf2f(v.y >> 16);
            s[i * 8 + 4] += bf2f(v.z & 0xFFFF); s[i * 8 + 5] += bf2f(v.z >> 16);
            s[i * 8 + 6] += bf2f(v.w & 0xFFFF); s[i * 8 + 7] += bf2f(v.w >> 16);
        }
    }

    const int w    = tid >> 6;
    const int lane = tid & 63;
    const int wm = w >> 1, wn = w & 1;
    const int m0 = mt * 128, n0 = nt * 128;
#pragma unroll
    for (int mf = 0; mf < 2; ++mf)
#pragma unroll
        for (int nf = 0; nf < 2; ++nf) {
            const int gcol = n0 + wn * 64 + nf * 32 + (lane & 31);
            const float bv = b[gcol];
#pragma unroll
            for (int r = 0; r < 16; ++r) {
                const int grow = m0 + wm * 64 + mf * 32 + (r & 3) + ((r >> 2) << 3)
                               + ((lane >> 5) << 2);
                const float val = s[(mf * 2 + nf) * 16 + r];
                out[(size_t)grow * FF + gcol] = val * d[grow] + bv;
            }
        }
}

// ---------------------------------------------------------------------------
extern "C" void kernel_launch(void* const* d_in, const int* in_sizes, int n_in,
                              void* d_out, int out_size, void* d_ws, size_t ws_size,
                              hipStream_t stream) {
    const float* x   = (const float*)d_in[0];   // [4096][512]
    const float* adj = (const float*)d_in[1];   // [4096][4096]
    const float* W   = (const float*)d_in[2];   // [512][512]
    const float* b   = (const float*)d_in[3];   // [512]
    float* out = (float*)d_out;                 // [4096][512] f32

    char* ws = (char*)d_ws;
    float*    d_    = (float*)ws;                                 // 16 KB (pad 64K)
    uint16_t* Abf   = (uint16_t*)(ws + 65536);                    // 32 MB
    uint16_t* zdT   = Abf + (size_t)NN * NN;                      // 4 MB
    uint16_t* xbf   = zdT + (size_t)FF * NN;                      // 4 MB
    uint16_t* Wbf   = xbf + (size_t)NN * FF;                      // 0.5 MB
    float*    z32   = (float*)(Wbf + (size_t)FF * FF);            // 8 MB
    uint16_t* parts = (uint16_t*)(z32 + (size_t)NN * FF);         // 16 MB packed tiles

    k_wc<<<FF * FF / 1024, 256, 0, stream>>>(W, Wbf);
    k_xc<<<NN * FF / 1024, 256, 0, stream>>>(x, xbf);
    k_prep<<<NN / 4, 256, 0, stream>>>(adj, d_, Abf);
    // z = x @ W^T
    k_mm<64, 64, FF><<<512, 256, 0, stream>>>(xbf, Wbf, z32);
    // zdT[n][k] = d_k * z[k][n] in bf16
    k_zt<<<dim3(NN / 64, FF / 64), 256, 0, stream>>>(z32, d_, zdT);
    // parts = A @ zdT^T  — LAUNCHED TWICE (idempotent) to measure t_mmx exactly
    k_mmx<<<512, 256, 0, stream>>>(Abf, zdT, parts);
    k_mmx<<<512, 256, 0, stream>>>(Abf, zdT, parts);
    // out = d[i] * sum_ks(parts) + b
    k_red<<<128, 256, 0, stream>>>(parts, d_, b, out);
}

// Round 11
// 77.084 us; speedup vs baseline: 1.2762x; 1.2762x over previous
//
#include <hip/hip_runtime.h>
#include <cstdint>

#define NN 4096
#define FF 512

typedef short bf16x8 __attribute__((ext_vector_type(8)));
typedef float f32x4 __attribute__((ext_vector_type(4)));

__device__ __forceinline__ uint16_t f2bf(float f) {
    uint32_t u = __builtin_bit_cast(uint32_t, f);
    u += 0x7FFFu + ((u >> 16) & 1u);   // round-to-nearest-even
    return (uint16_t)(u >> 16);
}
__device__ __forceinline__ float bf2f(uint32_t h) {
    uint32_t u = h << 16;
    return __builtin_bit_cast(float, u);
}

// ---------------------------------------------------------------------------
// k_prep: Abf[i][j] = bf16(adj[i][j] + (i==j)), d_i = rsqrt(1 + rowsum(adj))
// ---------------------------------------------------------------------------
__global__ __launch_bounds__(256) void k_prep(const float* __restrict__ adj,
                                              float* __restrict__ d,
                                              uint16_t* __restrict__ Abf) {
    const int row  = blockIdx.x * 4 + (threadIdx.x >> 6);
    const int lane = threadIdx.x & 63;
    const float4* p = (const float4*)(adj + (size_t)row * NN);
    float4 v[16];
    float s = 0.f;
#pragma unroll
    for (int i = 0; i < 16; ++i) {
        v[i] = p[lane + i * 64];
        s += (v[i].x + v[i].y) + (v[i].z + v[i].w);
    }
#pragma unroll
    for (int off = 1; off < 64; off <<= 1) s += __shfl_xor(s, off);
    const float di = rsqrtf(s + 1.0f);
    if (lane == 0) d[row] = di;
    uint16_t* outp = Abf + (size_t)row * NN;
#pragma unroll
    for (int i = 0; i < 16; ++i) {
        const int cb = (lane + i * 64) * 4;
        float a0 = v[i].x, a1 = v[i].y, a2 = v[i].z, a3 = v[i].w;
        if (cb + 0 == row) a0 += 1.0f;
        if (cb + 1 == row) a1 += 1.0f;
        if (cb + 2 == row) a2 += 1.0f;
        if (cb + 3 == row) a3 += 1.0f;
        ushort4 o;
        o.x = f2bf(a0); o.y = f2bf(a1); o.z = f2bf(a2); o.w = f2bf(a3);
        *(ushort4*)(outp + cb) = o;
    }
}

// ---------------------------------------------------------------------------
// k_xc / k_wc: f32 -> bf16 casts
// ---------------------------------------------------------------------------
__global__ __launch_bounds__(256) void k_xc(const float* __restrict__ x,
                                            uint16_t* __restrict__ xbf) {
    const size_t t4 = (size_t)blockIdx.x * 256 + threadIdx.x;
    float4 v = *(const float4*)(x + t4 * 4);
    ushort4 o;
    o.x = f2bf(v.x); o.y = f2bf(v.y); o.z = f2bf(v.z); o.w = f2bf(v.w);
    *(ushort4*)(xbf + t4 * 4) = o;
}

__global__ __launch_bounds__(256) void k_wc(const float* __restrict__ W,
                                            uint16_t* __restrict__ Wbf) {
    const size_t t4 = (size_t)blockIdx.x * 256 + threadIdx.x;
    float4 v = *(const float4*)(W + t4 * 4);
    ushort4 o;
    o.x = f2bf(v.x); o.y = f2bf(v.y); o.z = f2bf(v.z); o.w = f2bf(v.w);
    *(ushort4*)(Wbf + t4 * 4) = o;
}

// ---------------------------------------------------------------------------
// k_zt: zdT[n][k] = bf16(d[k] * z32[k][n])   (transpose+scale, via LDS)
// ---------------------------------------------------------------------------
__global__ __launch_bounds__(256) void k_zt(const float* __restrict__ z32,
                                            const float* __restrict__ d,
                                            uint16_t* __restrict__ zdT) {
    __shared__ uint16_t t[64][72];
    const int k0 = blockIdx.x * 64;
    const int n0 = blockIdx.y * 64;
    const int tid = threadIdx.x;
    const int r   = tid >> 4;
    const int c4  = tid & 15;
#pragma unroll
    for (int pass = 0; pass < 4; ++pass) {
        const int row = pass * 16 + r;
        float4 v = *(const float4*)(z32 + (size_t)(k0 + row) * FF + n0 + c4 * 4);
        const float dk = d[k0 + row];
        t[c4 * 4 + 0][row] = f2bf(v.x * dk);
        t[c4 * 4 + 1][row] = f2bf(v.y * dk);
        t[c4 * 4 + 2][row] = f2bf(v.z * dk);
        t[c4 * 4 + 3][row] = f2bf(v.w * dk);
    }
    __syncthreads();
#pragma unroll
    for (int pass = 0; pass < 2; ++pass) {
        const int cid = pass * 256 + tid;
        const int n  = cid >> 3;
        const int ch = cid & 7;
        *(uint4*)(zdT + (size_t)(n0 + n) * NN + k0 + ch * 8) = *(const uint4*)&t[n][ch * 8];
    }
}

// ---------------------------------------------------------------------------
// k_mm (small GEMM, R7-R10 verified): C = A[.][K] * Bt[.][K]^T, f32 out.
// ---------------------------------------------------------------------------
template <int BM, int BN, int K>
__global__ __launch_bounds__(256, 4) void k_mm(const uint16_t* __restrict__ A,
                                               const uint16_t* __restrict__ Bt,
                                               float* __restrict__ outp) {
    constexpr int NTC   = FF / BN;
    constexpr int NT    = K / 64;
    constexpr int MFR   = BM / 32;
    constexpr int NFR   = BN / 32;
    constexpr int LPT_A = BM / 32;
    constexpr int LPT_B = BN / 32;

    __shared__ uint16_t As[BM * 64];
    __shared__ uint16_t Bs[BN * 64];

    const int id   = blockIdx.x;
    const int mt   = id / NTC;
    const int nt   = id % NTC;
    const int m0 = mt * BM;
    const int n0 = nt * BN;

    const int tid  = threadIdx.x;
    const int w    = tid >> 6;
    const int lane = tid & 63;
    const int wm = w >> 1, wn = w & 1;

    f32x4 acc[MFR][NFR] = {};

    for (int t = 0; t < NT; ++t) {
        const int ktb = t * 64;
#pragma unroll
        for (int i = 0; i < LPT_A; ++i) {
            const int boff = i * 4096 + tid * 16;
            const int row  = boff >> 7;
            const int q    = (boff >> 4) & 7;
            const int c    = q ^ (row & 7);
            const uint16_t* src = A + (size_t)(m0 + row) * K + ktb + c * 8;
            __builtin_amdgcn_global_load_lds(
                (const __attribute__((address_space(1))) void*)src,
                (__attribute__((address_space(3))) void*)&As[boff >> 1],
                16, 0, 0);
        }
#pragma unroll
        for (int i = 0; i < LPT_B; ++i) {
            const int boff = i * 4096 + tid * 16;
            const int row  = boff >> 7;
            const int q    = (boff >> 4) & 7;
            const int c    = q ^ (row & 7);
            const uint16_t* src = Bt + (size_t)(n0 + row) * K + ktb + c * 8;
            __builtin_amdgcn_global_load_lds(
                (const __attribute__((address_space(1))) void*)src,
                (__attribute__((address_space(3))) void*)&Bs[boff >> 1],
                16, 0, 0);
        }
        __syncthreads();
#pragma unroll
        for (int kk = 0; kk < 2; ++kk) {
            const int cl = kk * 4 + (lane >> 4);
            bf16x8 af[MFR], bfr[NFR];
#pragma unroll
            for (int mf = 0; mf < MFR; ++mf) {
                const int r = wm * (MFR * 16) + mf * 16 + (lane & 15);
                af[mf] = *(const bf16x8*)&As[r * 64 + ((cl ^ (r & 7)) << 3)];
            }
#pragma unroll
            for (int nf = 0; nf < NFR; ++nf) {
                const int r = wn * (NFR * 16) + nf * 16 + (lane & 15);
                bfr[nf] = *(const bf16x8*)&Bs[r * 64 + ((cl ^ (r & 7)) << 3)];
            }
#pragma unroll
            for (int mf = 0; mf < MFR; ++mf)
#pragma unroll
                for (int nf = 0; nf < NFR; ++nf)
                    acc[mf][nf] = __builtin_amdgcn_mfma_f32_16x16x32_bf16(
                        af[mf], bfr[nf], acc[mf][nf], 0, 0, 0);
        }
        __syncthreads();
    }

    const int rbase = m0 + wm * (MFR * 16) + ((lane >> 4) << 2);
    const int cbase = n0 + wn * (NFR * 16) + (lane & 15);
#pragma unroll
    for (int mf = 0; mf < MFR; ++mf)
#pragma unroll
        for (int nf = 0; nf < NFR; ++nf) {
            const int col = cbase + nf * 16;
#pragma unroll
            for (int r = 0; r < 4; ++r) {
                const int row = rbase + mf * 16 + r;
                outp[(size_t)row * FF + col] = acc[mf][nf][r];
            }
        }
}

// ---------------------------------------------------------------------------
// k_mmx8: 8-phase 256^2 schedule (T3+T4+T5). parts[ks] = A @ zdT^T k-slice.
// 512 thr = 8 waves (2M x 4N), per-wave 128x64, 16x16x32 MFMA.
// LDS 128KB: [dbuf][A/B][half(128rows x 64 x bf16 = 16KB)], 8-slot XOR swizzle.
// Per K-tile, 4 phases: q0{rd A-lo(8)+B-lo(4); MFMA Alo.Blo} q1{rd B-hi; Alo.Bhi}
// q2{rd A-hi; Ahi.Bhi} q3{Ahi.Blo}. Stage order per tile [B0,A0,A1,B1] at
// lookahead 6 half-tiles; vmcnt(4) once per tile at q3 (never 0 until tail).
// Race-freedom: every region's stage issues >=1 barrier after its last reader
// (B0@q2>lastread q1; A0@q3>q2; A1@next-q0>q2; B1@next-q1>q1). setprio on MFMA.
// ---------------------------------------------------------------------------
__global__ __launch_bounds__(512, 2) void k_mmx8(const uint16_t* __restrict__ A,
                                                 const uint16_t* __restrict__ Bt,
                                                 uint16_t* __restrict__ parts) {
    constexpr int K = NN, SPLITK = 8;
    constexpr int KSLEN = K / SPLITK;   // 512
    constexpr int NT    = KSLEN / 64;   // 8 K-tiles
    constexpr int NS    = 4 * NT;       // 32 half-tile stages

    __shared__ uint16_t As[2][2][128 * 64];   // 64 KB
    __shared__ uint16_t Bs[2][2][128 * 64];   // 64 KB

    const int id   = blockIdx.x;        // 0..255
    const int ks   = id & 7;            // xcd = ks: B-slice (512KB) L2-resident/XCD
    const int slot = id >> 3;           // 0..31
    const int mt   = slot >> 1;         // 0..15
    const int nt   = slot & 1;          // 0..1
    const int m0 = mt * 256;
    const int n0 = nt * 256;
    const int k0 = ks * KSLEN;

    const int tid  = threadIdx.x;
    const int lane = tid & 63;
    const int w    = tid >> 6;
    const int wm   = w >> 2;            // 0..1
    const int wn   = w & 3;             // 0..3

    f32x4 acc[8][4] = {};

    // hs: 0 -> (B,half0), 1 -> (A,half0), 2 -> (A,half1), 3 -> (B,half1)
    auto STAGE = [&](int s) {
        if (s >= NS) return;
        const int Ts   = s >> 2;
        const int hs   = s & 3;
        const int db   = Ts & 1;
        const int ktb  = k0 + Ts * 64;
        const bool isA = (hs == 1) || (hs == 2);
        const int half = (hs >= 2) ? 1 : 0;
#pragma unroll
        for (int i = 0; i < 2; ++i) {
            const int boff = i * 8192 + tid * 16;   // 16KB half-tile
            const int row  = boff >> 7;             // 0..127
            const int q8   = (boff >> 4) & 7;
            const int c    = q8 ^ (row & 7);        // inverse-swizzled source
            if (isA) {
                const uint16_t* src = A + (size_t)(m0 + half * 128 + row) * K + ktb + c * 8;
                __builtin_amdgcn_global_load_lds(
                    (const __attribute__((address_space(1))) void*)src,
                    (__attribute__((address_space(3))) void*)&As[db][half][boff >> 1],
                    16, 0, 0);
            } else {
                const uint16_t* src = Bt + (size_t)(n0 + half * 128 + row) * K + ktb + c * 8;
                __builtin_amdgcn_global_load_lds(
                    (const __attribute__((address_space(1))) void*)src,
                    (__attribute__((address_space(3))) void*)&Bs[db][half][boff >> 1],
                    16, 0, 0);
            }
        }
    };

    auto RD_A = [&](bf16x8* dst, int db, int mh) {      // 4 mf x 2 kk = 8 b128
#pragma unroll
        for (int mf = 0; mf < 4; ++mf) {
            const int rr = mh * 64 + mf * 16 + (lane & 15);
#pragma unroll
            for (int kk = 0; kk < 2; ++kk) {
                const int cl = kk * 4 + (lane >> 4);
                dst[mf * 2 + kk] =
                    *(const bf16x8*)&As[db][wm][rr * 64 + ((cl ^ (rr & 7)) << 3)];
            }
        }
    };
    auto RD_B = [&](bf16x8* dst, int db, int nh) {      // 2 nf x 2 kk = 4 b128
#pragma unroll
        for (int nf = 0; nf < 2; ++nf) {
            const int rr = (wn & 1) * 64 + (nh * 2 + nf) * 16 + (lane & 15);
#pragma unroll
            for (int kk = 0; kk < 2; ++kk) {
                const int cl = kk * 4 + (lane >> 4);
                dst[nf * 2 + kk] =
                    *(const bf16x8*)&Bs[db][wn >> 1][rr * 64 + ((cl ^ (rr & 7)) << 3)];
            }
        }
    };
    auto MM = [&](const bf16x8* a, const bf16x8* b, int mh, int nh) {  // 16 MFMA
        __builtin_amdgcn_s_setprio(1);
#pragma unroll
        for (int mf = 0; mf < 4; ++mf)
#pragma unroll
            for (int nf = 0; nf < 2; ++nf)
#pragma unroll
                for (int kk = 0; kk < 2; ++kk)
                    acc[mh * 4 + mf][nh * 2 + nf] = __builtin_amdgcn_mfma_f32_16x16x32_bf16(
                        a[mf * 2 + kk], b[nf * 2 + kk], acc[mh * 4 + mf][nh * 2 + nf], 0, 0, 0);
        __builtin_amdgcn_s_setprio(0);
    };

    // prologue: 6 half-tiles staged (tile0 complete + tile1 B0,A0)
    STAGE(0); STAGE(1); STAGE(2); STAGE(3); STAGE(4); STAGE(5);
    asm volatile("s_waitcnt vmcnt(4)" ::: "memory");   // tile0 landed; s=4,5 in flight
    __builtin_amdgcn_s_barrier();

    for (int T = 0; T < NT; ++T) {
        const int db = T & 1;
        bf16x8 a_lo[8], a_hi[8], b_lo[4], b_hi[4];
        // q0
        STAGE(4 * T + 6);
        RD_A(a_lo, db, 0);
        RD_B(b_lo, db, 0);
        __builtin_amdgcn_s_barrier();
        MM(a_lo, b_lo, 0, 0);
        __builtin_amdgcn_s_barrier();
        // q1
        STAGE(4 * T + 7);
        RD_B(b_hi, db, 1);
        __builtin_amdgcn_s_barrier();
        MM(a_lo, b_hi, 0, 1);
        __builtin_amdgcn_s_barrier();
        // q2
        STAGE(4 * T + 8);
        RD_A(a_hi, db, 1);
        __builtin_amdgcn_s_barrier();
        MM(a_hi, b_hi, 1, 1);
        __builtin_amdgcn_s_barrier();
        // q3
        STAGE(4 * T + 9);
        if (T < NT - 2)       asm volatile("s_waitcnt vmcnt(4)" ::: "memory");
        else if (T == NT - 2) asm volatile("s_waitcnt vmcnt(0)" ::: "memory");
        __builtin_amdgcn_s_barrier();
        MM(a_hi, b_lo, 1, 0);
        __builtin_amdgcn_s_barrier();
    }

    // epilogue: packed 256 B/thread, frag-major (fi = mf*4+nf, r-minor)
    uint16_t* dst = parts + ((size_t)id * 512 + tid) * 128;
#pragma unroll
    for (int mf = 0; mf < 8; ++mf)
#pragma unroll
        for (int nf = 0; nf < 4; nf += 2) {
            uint32_t w0 = (uint32_t)f2bf(acc[mf][nf][0])     | ((uint32_t)f2bf(acc[mf][nf][1]) << 16);
            uint32_t w1 = (uint32_t)f2bf(acc[mf][nf][2])     | ((uint32_t)f2bf(acc[mf][nf][3]) << 16);
            uint32_t w2 = (uint32_t)f2bf(acc[mf][nf + 1][0]) | ((uint32_t)f2bf(acc[mf][nf + 1][1]) << 16);
            uint32_t w3 = (uint32_t)f2bf(acc[mf][nf + 1][2]) | ((uint32_t)f2bf(acc[mf][nf + 1][3]) << 16);
            uint4 v = {w0, w1, w2, w3};
            *(uint4*)(dst + (mf * 4 + nf) * 4) = v;
        }
}

// ---------------------------------------------------------------------------
// k_red: out = d[i] * sum_ks(parts) + b. 4 threads share one mmx-thread's
// 256B (64B each, coalesced); fixed ks order -> deterministic.
// ---------------------------------------------------------------------------
__global__ __launch_bounds__(256) void k_red(const uint16_t* __restrict__ parts,
                                             const float* __restrict__ d,
                                             const float* __restrict__ b,
                                             float* __restrict__ out) {
    const int gid  = blockIdx.x * 256 + threadIdx.x;   // 0..65535
    const int pair = gid >> 2;                          // (slot, mmx_tid)
    const int qq   = gid & 3;
    const int slot = pair >> 9;                         // 0..31
    const int mtid = pair & 511;

    float s[32];
#pragma unroll
    for (int i = 0; i < 32; ++i) s[i] = 0.f;
#pragma unroll
    for (int ks = 0; ks < 8; ++ks) {
        const uint16_t* src = parts + ((size_t)(slot * 8 + ks) * 512 + mtid) * 128 + qq * 32;
        const uint4* sv = (const uint4*)src;
#pragma unroll
        for (int j = 0; j < 4; ++j) {
            uint4 v = sv[j];
            s[j * 8 + 0] += bf2f(v.x & 0xFFFF); s[j * 8 + 1] += bf2f(v.x >> 16);
            s[j * 8 + 2] += bf2f(v.y & 0xFFFF); s[j * 8 + 3] += bf2f(v.y >> 16);
            s[j * 8 + 4] += bf2f(v.z & 0xFFFF); s[j * 8 + 5] += bf2f(v.z >> 16);
            s[j * 8 + 6] += bf2f(v.w & 0xFFFF); s[j * 8 + 7] += bf2f(v.w >> 16);
        }
    }

    const int lane = mtid & 63;
    const int w    = mtid >> 6;
    const int wm = w >> 2, wn = w & 3;
    const int mt = slot >> 1, nt = slot & 1;
#pragma unroll
    for (int f = 0; f < 8; ++f) {
        const int fi = qq * 8 + f;
        const int mf = fi >> 2, nf = fi & 3;
        const int gr0 = mt * 256 + wm * 128 + mf * 16 + ((lane >> 4) << 2);
        const int gc  = nt * 256 + wn * 64 + nf * 16 + (lane & 15);
        const float bv = b[gc];
#pragma unroll
        for (int r = 0; r < 4; ++r) {
            const int grow = gr0 + r;
            out[(size_t)grow * FF + gc] = s[f * 4 + r] * d[grow] + bv;
        }
    }
}

// ---------------------------------------------------------------------------
extern "C" void kernel_launch(void* const* d_in, const int* in_sizes, int n_in,
                              void* d_out, int out_size, void* d_ws, size_t ws_size,
                              hipStream_t stream) {
    const float* x   = (const float*)d_in[0];   // [4096][512]
    const float* adj = (const float*)d_in[1];   // [4096][4096]
    const float* W   = (const float*)d_in[2];   // [512][512]
    const float* b   = (const float*)d_in[3];   // [512]
    float* out = (float*)d_out;                 // [4096][512] f32

    char* ws = (char*)d_ws;
    float*    d_    = (float*)ws;                                 // 16 KB (pad 64K)
    uint16_t* Abf   = (uint16_t*)(ws + 65536);                    // 32 MB
    uint16_t* zdT   = Abf + (size_t)NN * NN;                      // 4 MB
    uint16_t* xbf   = zdT + (size_t)FF * NN;                      // 4 MB
    uint16_t* Wbf   = xbf + (size_t)NN * FF;                      // 0.5 MB
    float*    z32   = (float*)(Wbf + (size_t)FF * FF);            // 8 MB ─┐ union
    uint16_t* parts = (uint16_t*)z32;                             // 32 MB ┘ (z32 dead
                                                                  //  before k_mmx8 runs)

    k_wc<<<FF * FF / 1024, 256, 0, stream>>>(W, Wbf);
    k_xc<<<NN * FF / 1024, 256, 0, stream>>>(x, xbf);
    k_prep<<<NN / 4, 256, 0, stream>>>(adj, d_, Abf);
    // z = x @ W^T
    k_mm<64, 64, FF><<<512, 256, 0, stream>>>(xbf, Wbf, z32);
    // zdT[n][k] = d_k * z[k][n] in bf16 (z32 fully consumed here)
    k_zt<<<dim3(NN / 64, FF / 64), 256, 0, stream>>>(z32, d_, zdT);
    // parts[ks] = A @ zdT^T, 8-phase 256^2 schedule
    k_mmx8<<<256, 512, 0, stream>>>(Abf, zdT, parts);
    // out = d[i] * sum_ks(parts) + b
    k_red<<<256, 256, 0, stream>>>(parts, d_, b, out);
}

// Round 12
// 70.202 us; speedup vs baseline: 1.4013x; 1.0980x over previous
//
#include <hip/hip_runtime.h>
#include <cstdint>

#define NN 4096
#define FF 512

typedef short bf16x8 __attribute__((ext_vector_type(8)));
typedef float f32x4 __attribute__((ext_vector_type(4)));
typedef float f32x16 __attribute__((ext_vector_type(16)));

__device__ __forceinline__ uint16_t f2bf(float f) {
    uint32_t u = __builtin_bit_cast(uint32_t, f);
    u += 0x7FFFu + ((u >> 16) & 1u);   // round-to-nearest-even
    return (uint16_t)(u >> 16);
}
__device__ __forceinline__ float bf2f(uint32_t h) {
    uint32_t u = h << 16;
    return __builtin_bit_cast(float, u);
}

// ---------------------------------------------------------------------------
// k_prep: Abf[i][j] = bf16(adj[i][j] + (i==j)), d_i = rsqrt(1 + rowsum(adj))
// (read adj once; 96 MB total ≈ HBM floor for this step)
// ---------------------------------------------------------------------------
__global__ __launch_bounds__(256) void k_prep(const float* __restrict__ adj,
                                              float* __restrict__ d,
                                              uint16_t* __restrict__ Abf) {
    const int row  = blockIdx.x * 4 + (threadIdx.x >> 6);
    const int lane = threadIdx.x & 63;
    const float4* p = (const float4*)(adj + (size_t)row * NN);
    float4 v[16];
    float s = 0.f;
#pragma unroll
    for (int i = 0; i < 16; ++i) {
        v[i] = p[lane + i * 64];
        s += (v[i].x + v[i].y) + (v[i].z + v[i].w);
    }
#pragma unroll
    for (int off = 1; off < 64; off <<= 1) s += __shfl_xor(s, off);
    const float di = rsqrtf(s + 1.0f);
    if (lane == 0) d[row] = di;
    uint16_t* outp = Abf + (size_t)row * NN;
#pragma unroll
    for (int i = 0; i < 16; ++i) {
        const int cb = (lane + i * 64) * 4;
        float a0 = v[i].x, a1 = v[i].y, a2 = v[i].z, a3 = v[i].w;
        if (cb + 0 == row) a0 += 1.0f;
        if (cb + 1 == row) a1 += 1.0f;
        if (cb + 2 == row) a2 += 1.0f;
        if (cb + 3 == row) a3 += 1.0f;
        ushort4 o;
        o.x = f2bf(a0); o.y = f2bf(a1); o.z = f2bf(a2); o.w = f2bf(a3);
        *(ushort4*)(outp + cb) = o;
    }
}

// ---------------------------------------------------------------------------
// k_xc / k_wc: f32 -> bf16 casts
// ---------------------------------------------------------------------------
__global__ __launch_bounds__(256) void k_xc(const float* __restrict__ x,
                                            uint16_t* __restrict__ xbf) {
    const size_t t4 = (size_t)blockIdx.x * 256 + threadIdx.x;
    float4 v = *(const float4*)(x + t4 * 4);
    ushort4 o;
    o.x = f2bf(v.x); o.y = f2bf(v.y); o.z = f2bf(v.z); o.w = f2bf(v.w);
    *(ushort4*)(xbf + t4 * 4) = o;
}

__global__ __launch_bounds__(256) void k_wc(const float* __restrict__ W,
                                            uint16_t* __restrict__ Wbf) {
    const size_t t4 = (size_t)blockIdx.x * 256 + threadIdx.x;
    float4 v = *(const float4*)(W + t4 * 4);
    ushort4 o;
    o.x = f2bf(v.x); o.y = f2bf(v.y); o.z = f2bf(v.z); o.w = f2bf(v.w);
    *(ushort4*)(Wbf + t4 * 4) = o;
}

// ---------------------------------------------------------------------------
// k_mmz: fused small GEMM + transpose + d-scale.
// zdT[n][k] = bf16( d[k] * (x @ W^T)[k][n] )   (kills the separate k_zt pass)
// Main loop = R7-R11-verified k_mm<64,64,512>; epilogue transposes via LDS.
// ---------------------------------------------------------------------------
__global__ __launch_bounds__(256, 4) void k_mmz(const uint16_t* __restrict__ A,
                                                const uint16_t* __restrict__ Bt,
                                                const float* __restrict__ d,
                                                uint16_t* __restrict__ zdT) {
    constexpr int BM = 64, BN = 64, K = FF;
    constexpr int NTC = FF / BN;          // 8
    constexpr int NT  = K / 64;           // 8

    __shared__ uint16_t As[BM * 64];
    __shared__ uint16_t Bs[BN * 64];
    __shared__ uint16_t tt[64][80];       // transpose buffer (160B rows, 32B-aligned)

    const int id = blockIdx.x;
    const int mt = id / NTC;
    const int nt = id % NTC;
    const int m0 = mt * BM;               // k-range of x
    const int n0 = nt * BN;               // n-range (rows of W)

    const int tid  = threadIdx.x;
    const int w    = tid >> 6;
    const int lane = tid & 63;
    const int wm = w >> 1, wn = w & 1;

    f32x4 acc[2][2] = {};

    for (int t = 0; t < NT; ++t) {
        const int ktb = t * 64;
#pragma unroll
        for (int i = 0; i < 2; ++i) {
            const int boff = i * 4096 + tid * 16;
            const int row  = boff >> 7;
            const int q    = (boff >> 4) & 7;
            const int c    = q ^ (row & 7);
            const uint16_t* src = A + (size_t)(m0 + row) * K + ktb + c * 8;
            __builtin_amdgcn_global_load_lds(
                (const __attribute__((address_space(1))) void*)src,
                (__attribute__((address_space(3))) void*)&As[boff >> 1],
                16, 0, 0);
        }
#pragma unroll
        for (int i = 0; i < 2; ++i) {
            const int boff = i * 4096 + tid * 16;
            const int row  = boff >> 7;
            const int q    = (boff >> 4) & 7;
            const int c    = q ^ (row & 7);
            const uint16_t* src = Bt + (size_t)(n0 + row) * K + ktb + c * 8;
            __builtin_amdgcn_global_load_lds(
                (const __attribute__((address_space(1))) void*)src,
                (__attribute__((address_space(3))) void*)&Bs[boff >> 1],
                16, 0, 0);
        }
        __syncthreads();
#pragma unroll
        for (int kk = 0; kk < 2; ++kk) {
            const int cl = kk * 4 + (lane >> 4);
            bf16x8 af[2], bfr[2];
#pragma unroll
            for (int mf = 0; mf < 2; ++mf) {
                const int r = wm * 32 + mf * 16 + (lane & 15);
                af[mf] = *(const bf16x8*)&As[r * 64 + ((cl ^ (r & 7)) << 3)];
            }
#pragma unroll
            for (int nf = 0; nf < 2; ++nf) {
                const int r = wn * 32 + nf * 16 + (lane & 15);
                bfr[nf] = *(const bf16x8*)&Bs[r * 64 + ((cl ^ (r & 7)) << 3)];
            }
#pragma unroll
            for (int mf = 0; mf < 2; ++mf)
#pragma unroll
                for (int nf = 0; nf < 2; ++nf)
                    acc[mf][nf] = __builtin_amdgcn_mfma_f32_16x16x32_bf16(
                        af[mf], bfr[nf], acc[mf][nf], 0, 0, 0);
        }
        __syncthreads();
    }

    // epilogue: tt[n_local][k_local] = bf16(acc * d[k]); then coalesced zdT rows
    const int rb = wm * 32 + ((lane >> 4) << 2);
    const int cb = wn * 32 + (lane & 15);
#pragma unroll
    for (int mf = 0; mf < 2; ++mf)
#pragma unroll
        for (int nf = 0; nf < 2; ++nf) {
            const int col_l = cb + nf * 16;
#pragma unroll
            for (int r = 0; r < 4; ++r) {
                const int row_l = rb + mf * 16 + r;
                tt[col_l][row_l] = f2bf(acc[mf][nf][r] * d[m0 + row_l]);
            }
        }
    __syncthreads();
    const int n_l = tid >> 2;
    const int ch  = tid & 3;
    uint4* dst = (uint4*)(zdT + (size_t)(n0 + n_l) * NN + m0 + ch * 16);
    dst[0] = *(const uint4*)&tt[n_l][ch * 16];
    dst[1] = *(const uint4*)&tt[n_l][ch * 16 + 8];
}

// ---------------------------------------------------------------------------
// k_mmx: big GEMM, L3-traffic-halved geometry.
// parts[ks] = A[4096][512-slice] @ zdT[512][512-slice]^T  (bf16 in/out)
// BM=128, BN=256 (A re-read x2 instead of x4 through L3), BK=32,
// 512 thr = 8 waves (2m x 4n), per-wave 64x64 = 2x2 of 32x32x16 frags
// (R3/R4/R9-verified math; 85 FLOP/staged-byte).
// Double-buffer 48KB -> 2 blocks/CU (cap 3); ring-2 counted vmcnt(3).
// 4-slot XOR chunk swizzle on 64B rows [R6-verified]. Split-K=8.
// ---------------------------------------------------------------------------
__global__ __launch_bounds__(512, 2) void k_mmx(const uint16_t* __restrict__ A,
                                                const uint16_t* __restrict__ Bt,
                                                uint16_t* __restrict__ parts) {
    constexpr int BM = 128, BN = 256, K = NN, SPLITK = 8;
    constexpr int KSLEN = K / SPLITK;     // 512
    constexpr int NT    = KSLEN / 32;     // 16

    __shared__ uint16_t As[2][BM * 32];   // 2 x 8 KB
    __shared__ uint16_t Bs[2][BN * 32];   // 2 x 16 KB

    // XCD-grouped: id&7 = XCD; each XCD owns 4 m-stripes x (2 nt x 8 ks).
    const int id   = blockIdx.x;          // 0..511
    const int xcd  = id & 7;
    const int slot = id >> 3;             // 0..63
    const int mt   = xcd * 4 + (slot >> 4);
    const int rem  = slot & 15;
    const int ks   = rem >> 1;            // 0..7
    const int nt   = rem & 1;             // 0..1
    const int m0 = mt * BM;
    const int n0 = nt * BN;
    const int k0 = ks * KSLEN;

    const int tid  = threadIdx.x;
    const int w    = tid >> 6;
    const int lane = tid & 63;
    const int wm = w >> 2, wn = w & 3;    // 2m x 4n

    f32x16 acc[2][2] = {};

    auto STAGE = [&](int t, int buf) {
        const int ktb = k0 + t * 32;
        {   // A: 8 KB, 1 load/thread
            const int boff = tid * 16;
            const int row  = boff >> 6;        // 64 B rows
            const int q    = (boff >> 4) & 3;
            const int c    = q ^ (row & 3);
            const uint16_t* src = A + (size_t)(m0 + row) * K + ktb + c * 8;
            __builtin_amdgcn_global_load_lds(
                (const __attribute__((address_space(1))) void*)src,
                (__attribute__((address_space(3))) void*)&As[buf][boff >> 1],
                16, 0, 0);
        }
#pragma unroll
        for (int i = 0; i < 2; ++i) {          // B: 16 KB, 2 loads/thread
            const int boff = i * 8192 + tid * 16;
            const int row  = boff >> 6;        // 0..255
            const int q    = (boff >> 4) & 3;
            const int c    = q ^ (row & 3);
            const uint16_t* src = Bt + (size_t)(n0 + row) * K + ktb + c * 8;
            __builtin_amdgcn_global_load_lds(
                (const __attribute__((address_space(1))) void*)src,
                (__attribute__((address_space(3))) void*)&Bs[buf][boff >> 1],
                16, 0, 0);
        }
    };

    auto COMPUTE = [&](int buf) {
#pragma unroll
        for (int kk = 0; kk < 2; ++kk) {       // 2 k-slices of 16
            const int cl = kk * 2 + (lane >> 5);   // chunk 0..3
            bf16x8 af[2], bfr[2];
#pragma unroll
            for (int mf = 0; mf < 2; ++mf) {
                const int r = wm * 64 + mf * 32 + (lane & 31);
                af[mf] = *(const bf16x8*)&As[buf][r * 32 + ((cl ^ (r & 3)) << 3)];
            }
#pragma unroll
            for (int nf = 0; nf < 2; ++nf) {
                const int r = wn * 64 + nf * 32 + (lane & 31);
                bfr[nf] = *(const bf16x8*)&Bs[buf][r * 32 + ((cl ^ (r & 3)) << 3)];
            }
#pragma unroll
            for (int mf = 0; mf < 2; ++mf)
#pragma unroll
                for (int nf = 0; nf < 2; ++nf)
                    acc[mf][nf] = __builtin_amdgcn_mfma_f32_32x32x16_bf16(
                        af[mf], bfr[nf], acc[mf][nf], 0, 0, 0);
        }
    };

    STAGE(0, 0);
    for (int t = 0; t < NT - 1; ++t) {
        STAGE(t + 1, (t + 1) & 1);
        asm volatile("s_waitcnt vmcnt(3)" ::: "memory");  // next tile's 3 in flight
        __builtin_amdgcn_s_barrier();
        COMPUTE(t & 1);
        __builtin_amdgcn_s_barrier();
    }
    asm volatile("s_waitcnt vmcnt(0)" ::: "memory");
    __builtin_amdgcn_s_barrier();
    COMPUTE((NT - 1) & 1);

    // epilogue: bf16 partials; 32x32 C/D: col=lane&31, row=(r&3)+8*(r>>2)+4*(lane>>5)
    uint16_t* dst = parts + (size_t)ks * NN * FF;
    const int rb = m0 + wm * 64 + ((lane >> 5) << 2);
    const int cb = n0 + wn * 64 + (lane & 31);
#pragma unroll
    for (int mf = 0; mf < 2; ++mf)
#pragma unroll
        for (int nf = 0; nf < 2; ++nf) {
            const int gcol = cb + nf * 32;
#pragma unroll
            for (int r = 0; r < 16; ++r) {
                const int grow = rb + mf * 32 + (r & 3) + ((r >> 2) << 3);
                dst[(size_t)grow * FF + gcol] = f2bf(acc[mf][nf][r]);
            }
        }
}

// ---------------------------------------------------------------------------
// k_red: out[i][j] = d[i] * sum_{p=0..7} bf2f(parts[p][i][j]) + b[j]
// ---------------------------------------------------------------------------
__global__ __launch_bounds__(256) void k_red(const uint16_t* __restrict__ parts,
                                             const float* __restrict__ d,
                                             const float* __restrict__ b,
                                             float* __restrict__ out) {
    constexpr size_t STRIDE = (size_t)NN * FF;
    const size_t g   = (size_t)blockIdx.x * 256 + threadIdx.x;   // ushort8 id
    const int    row = (int)((g * 8) >> 9);
    const int    col = (int)((g * 8) & 511);
    float s[8] = {};
#pragma unroll
    for (int p = 0; p < 8; ++p) {
        ushort4 v0 = *(const ushort4*)(parts + p * STRIDE + g * 8);
        ushort4 v1 = *(const ushort4*)(parts + p * STRIDE + g * 8 + 4);
        s[0] += bf2f(v0.x); s[1] += bf2f(v0.y); s[2] += bf2f(v0.z); s[3] += bf2f(v0.w);
        s[4] += bf2f(v1.x); s[5] += bf2f(v1.y); s[6] += bf2f(v1.z); s[7] += bf2f(v1.w);
    }
    const float di = d[row];
    float4 o0, o1;
    o0.x = s[0] * di + b[col + 0];
    o0.y = s[1] * di + b[col + 1];
    o0.z = s[2] * di + b[col + 2];
    o0.w = s[3] * di + b[col + 3];
    o1.x = s[4] * di + b[col + 4];
    o1.y = s[5] * di + b[col + 5];
    o1.z = s[6] * di + b[col + 6];
    o1.w = s[7] * di + b[col + 7];
    *(float4*)(out + g * 8)     = o0;
    *(float4*)(out + g * 8 + 4) = o1;
}

// ---------------------------------------------------------------------------
extern "C" void kernel_launch(void* const* d_in, const int* in_sizes, int n_in,
                              void* d_out, int out_size, void* d_ws, size_t ws_size,
                              hipStream_t stream) {
    const float* x   = (const float*)d_in[0];   // [4096][512]
    const float* adj = (const float*)d_in[1];   // [4096][4096]
    const float* W   = (const float*)d_in[2];   // [512][512]
    const float* b   = (const float*)d_in[3];   // [512]
    float* out = (float*)d_out;                 // [4096][512] f32

    char* ws = (char*)d_ws;
    float*    d_    = (float*)ws;                                 // 16 KB (pad 64K)
    uint16_t* Abf   = (uint16_t*)(ws + 65536);                    // 32 MB
    uint16_t* zdT   = Abf + (size_t)NN * NN;                      // 4 MB
    uint16_t* xbf   = zdT + (size_t)FF * NN;                      // 4 MB
    uint16_t* Wbf   = xbf + (size_t)NN * FF;                      // 0.5 MB
    uint16_t* parts = Wbf + (size_t)FF * FF;                      // 32 MB (8 x 4MB bf16)

    k_wc<<<FF * FF / 1024, 256, 0, stream>>>(W, Wbf);
    k_xc<<<NN * FF / 1024, 256, 0, stream>>>(x, xbf);
    k_prep<<<NN / 4, 256, 0, stream>>>(adj, d_, Abf);
    // zdT[n][k] = d_k * (x @ W^T)[k][n]   (fused GEMM + transpose + scale)
    k_mmz<<<512, 256, 0, stream>>>(xbf, Wbf, d_, zdT);
    // parts[ks] = A @ zdT^T k-slice  (BN=256: A L3-traffic halved)
    k_mmx<<<512, 512, 0, stream>>>(Abf, zdT, parts);
    // out = d[i] * sum_ks(parts) + b
    k_red<<<NN * FF / 2048, 256, 0, stream>>>(parts, d_, b, out);
}

// Round 13
// 69.136 us; speedup vs baseline: 1.4229x; 1.0154x over previous
//
#include <hip/hip_runtime.h>
#include <cstdint>

#define NN 4096
#define FF 512

typedef short bf16x8 __attribute__((ext_vector_type(8)));
typedef float f32x4 __attribute__((ext_vector_type(4)));
typedef float f32x16 __attribute__((ext_vector_type(16)));

__device__ __forceinline__ uint16_t f2bf(float f) {
    uint32_t u = __builtin_bit_cast(uint32_t, f);
    u += 0x7FFFu + ((u >> 16) & 1u);   // round-to-nearest-even
    return (uint16_t)(u >> 16);
}
__device__ __forceinline__ float bf2f(uint32_t h) {
    uint32_t u = h << 16;
    return __builtin_bit_cast(float, u);
}

// ---------------------------------------------------------------------------
// k_dsum: d_i = rsqrt(1 + rowsum(adj)).  Read-only 64 MB pass (~10.3 µs);
// also warms L3 with adj for k_mmx's direct-f32 A reads.
// ---------------------------------------------------------------------------
__global__ __launch_bounds__(256) void k_dsum(const float* __restrict__ adj,
                                              float* __restrict__ d) {
    const int row  = blockIdx.x * 4 + (threadIdx.x >> 6);
    const int lane = threadIdx.x & 63;
    const float4* p = (const float4*)(adj + (size_t)row * NN);
    float s = 0.f;
#pragma unroll
    for (int i = 0; i < 16; ++i) {
        float4 v = p[lane + i * 64];
        s += (v.x + v.y) + (v.z + v.w);
    }
#pragma unroll
    for (int off = 1; off < 64; off <<= 1) s += __shfl_xor(s, off);
    if (lane == 0) d[row] = rsqrtf(s + 1.0f);
}

// ---------------------------------------------------------------------------
// k_xc / k_wc: f32 -> bf16 casts
// ---------------------------------------------------------------------------
__global__ __launch_bounds__(256) void k_xc(const float* __restrict__ x,
                                            uint16_t* __restrict__ xbf) {
    const size_t t4 = (size_t)blockIdx.x * 256 + threadIdx.x;
    float4 v = *(const float4*)(x + t4 * 4);
    ushort4 o;
    o.x = f2bf(v.x); o.y = f2bf(v.y); o.z = f2bf(v.z); o.w = f2bf(v.w);
    *(ushort4*)(xbf + t4 * 4) = o;
}

__global__ __launch_bounds__(256) void k_wc(const float* __restrict__ W,
                                            uint16_t* __restrict__ Wbf) {
    const size_t t4 = (size_t)blockIdx.x * 256 + threadIdx.x;
    float4 v = *(const float4*)(W + t4 * 4);
    ushort4 o;
    o.x = f2bf(v.x); o.y = f2bf(v.y); o.z = f2bf(v.z); o.w = f2bf(v.w);
    *(ushort4*)(Wbf + t4 * 4) = o;
}

// ---------------------------------------------------------------------------
// k_mmz: fused small GEMM + transpose + d-scale (R12-verified).
// zdT[n][k] = bf16( d[k] * (x @ W^T)[k][n] )
// ---------------------------------------------------------------------------
__global__ __launch_bounds__(256, 4) void k_mmz(const uint16_t* __restrict__ A,
                                                const uint16_t* __restrict__ Bt,
                                                const float* __restrict__ d,
                                                uint16_t* __restrict__ zdT) {
    constexpr int BM = 64, BN = 64, K = FF;
    constexpr int NTC = FF / BN;          // 8
    constexpr int NT  = K / 64;           // 8

    __shared__ uint16_t As[BM * 64];
    __shared__ uint16_t Bs[BN * 64];
    __shared__ uint16_t tt[64][80];

    const int id = blockIdx.x;
    const int mt = id / NTC;
    const int nt = id % NTC;
    const int m0 = mt * BM;
    const int n0 = nt * BN;

    const int tid  = threadIdx.x;
    const int w    = tid >> 6;
    const int lane = tid & 63;
    const int wm = w >> 1, wn = w & 1;

    f32x4 acc[2][2] = {};

    for (int t = 0; t < NT; ++t) {
        const int ktb = t * 64;
#pragma unroll
        for (int i = 0; i < 2; ++i) {
            const int boff = i * 4096 + tid * 16;
            const int row  = boff >> 7;
            const int q    = (boff >> 4) & 7;
            const int c    = q ^ (row & 7);
            const uint16_t* src = A + (size_t)(m0 + row) * K + ktb + c * 8;
            __builtin_amdgcn_global_load_lds(
                (const __attribute__((address_space(1))) void*)src,
                (__attribute__((address_space(3))) void*)&As[boff >> 1],
                16, 0, 0);
        }
#pragma unroll
        for (int i = 0; i < 2; ++i) {
            const int boff = i * 4096 + tid * 16;
            const int row  = boff >> 7;
            const int q    = (boff >> 4) & 7;
            const int c    = q ^ (row & 7);
            const uint16_t* src = Bt + (size_t)(n0 + row) * K + ktb + c * 8;
            __builtin_amdgcn_global_load_lds(
                (const __attribute__((address_space(1))) void*)src,
                (__attribute__((address_space(3))) void*)&Bs[boff >> 1],
                16, 0, 0);
        }
        __syncthreads();
#pragma unroll
        for (int kk = 0; kk < 2; ++kk) {
            const int cl = kk * 4 + (lane >> 4);
            bf16x8 af[2], bfr[2];
#pragma unroll
            for (int mf = 0; mf < 2; ++mf) {
                const int r = wm * 32 + mf * 16 + (lane & 15);
                af[mf] = *(const bf16x8*)&As[r * 64 + ((cl ^ (r & 7)) << 3)];
            }
#pragma unroll
            for (int nf = 0; nf < 2; ++nf) {
                const int r = wn * 32 + nf * 16 + (lane & 15);
                bfr[nf] = *(const bf16x8*)&Bs[r * 64 + ((cl ^ (r & 7)) << 3)];
            }
#pragma unroll
            for (int mf = 0; mf < 2; ++mf)
#pragma unroll
                for (int nf = 0; nf < 2; ++nf)
                    acc[mf][nf] = __builtin_amdgcn_mfma_f32_16x16x32_bf16(
                        af[mf], bfr[nf], acc[mf][nf], 0, 0, 0);
        }
        __syncthreads();
    }

    const int rb = wm * 32 + ((lane >> 4) << 2);
    const int cb = wn * 32 + (lane & 15);
#pragma unroll
    for (int mf = 0; mf < 2; ++mf)
#pragma unroll
        for (int nf = 0; nf < 2; ++nf) {
            const int col_l = cb + nf * 16;
#pragma unroll
            for (int r = 0; r < 4; ++r) {
                const int row_l = rb + mf * 16 + r;
                tt[col_l][row_l] = f2bf(acc[mf][nf][r] * d[m0 + row_l]);
            }
        }
    __syncthreads();
    const int n_l = tid >> 2;
    const int ch  = tid & 3;
    uint4* dst = (uint4*)(zdT + (size_t)(n0 + n_l) * NN + m0 + ch * 16);
    dst[0] = *(const uint4*)&tt[n_l][ch * 16];
    dst[1] = *(const uint4*)&tt[n_l][ch * 16 + 8];
}

// ---------------------------------------------------------------------------
// k_mmx: big GEMM, A read DIRECTLY from f32 adj (L3-resident after k_dsum),
// converted to bf16 + diag-add inline, reg-staged with swizzled ds_write_b128.
// parts[ks] = (adj+I) @ zdT^T k-slice.  B via gload_lds (R12-verified path).
// BM=128, BN=256, BK=32, 512 thr = 8 waves (2m x 4n), 32x32x16 frags.
// Double-buffer; A(t+2) loads + B(t+1) gloads issued ahead (T14 cover).
// 4-slot XOR swizzle both operands. Split-K=8, bf16 partials, k_red reduces.
// ---------------------------------------------------------------------------
__global__ __launch_bounds__(512, 2) void k_mmx(const float* __restrict__ adjf,
                                                const uint16_t* __restrict__ Bt,
                                                uint16_t* __restrict__ parts) {
    constexpr int BM = 128, BN = 256, K = NN, SPLITK = 8;
    constexpr int KSLEN = K / SPLITK;     // 512
    constexpr int NT    = KSLEN / 32;     // 16

    __shared__ uint16_t As[2][BM * 32];   // 2 x 8 KB
    __shared__ uint16_t Bs[2][BN * 32];   // 2 x 16 KB

    const int id   = blockIdx.x;          // 0..511
    const int xcd  = id & 7;
    const int slot = id >> 3;
    const int mt   = xcd * 4 + (slot >> 4);
    const int rem  = slot & 15;
    const int ks   = rem >> 1;
    const int nt   = rem & 1;
    const int m0 = mt * BM;
    const int n0 = nt * BN;
    const int k0 = ks * KSLEN;

    const int tid  = threadIdx.x;
    const int w    = tid >> 6;
    const int lane = tid & 63;
    const int wm = w >> 2, wn = w & 3;

    // A reg-stage mapping: thread -> (row, 8-col chunk)
    const int arow = tid >> 2;            // 0..127
    const int ac   = tid & 3;             // chunk
    const int aq   = ac ^ (arow & 3);     // swizzled LDS slot
    const float* asrc = adjf + (size_t)(m0 + arow) * NN + k0 + ac * 8;
    const int diagbase = (m0 + arow) - k0 - ac * 8;   // dj = diagbase - T*32

    f32x16 acc[2][2] = {};
    float4 ar0, ar1;

    auto GLB_A = [&](int T) {             // issue A-tile T f32 loads -> regs
        ar0 = *(const float4*)(asrc + T * 32);
        ar1 = *(const float4*)(asrc + T * 32 + 4);
    };
    auto CVT_WRITE = [&](int T, int buf) {   // aregs (tile T) -> LDS, +diag
        float a[8] = {ar0.x, ar0.y, ar0.z, ar0.w, ar1.x, ar1.y, ar1.z, ar1.w};
        const int dj = diagbase - T * 32;
#pragma unroll
        for (int j = 0; j < 8; ++j) a[j] += (dj == j) ? 1.0f : 0.0f;
        uint32_t w0 = (uint32_t)f2bf(a[0]) | ((uint32_t)f2bf(a[1]) << 16);
        uint32_t w1 = (uint32_t)f2bf(a[2]) | ((uint32_t)f2bf(a[3]) << 16);
        uint32_t w2 = (uint32_t)f2bf(a[4]) | ((uint32_t)f2bf(a[5]) << 16);
        uint32_t w3 = (uint32_t)f2bf(a[6]) | ((uint32_t)f2bf(a[7]) << 16);
        uint4 v = {w0, w1, w2, w3};
        *(uint4*)&As[buf][arow * 32 + aq * 8] = v;
    };
    auto GLB_B = [&](int t, int buf) {    // B: 16 KB via gload_lds
#pragma unroll
        for (int i = 0; i < 2; ++i) {
            const int boff = i * 8192 + tid * 16;
            const int row  = boff >> 6;
            const int q    = (boff >> 4) & 3;
            const int c    = q ^ (row & 3);
            const uint16_t* src = Bt + (size_t)(n0 + row) * K + k0 + t * 32 + c * 8;
            __builtin_amdgcn_global_load_lds(
                (const __attribute__((address_space(1))) void*)src,
                (__attribute__((address_space(3))) void*)&Bs[buf][boff >> 1],
                16, 0, 0);
        }
    };
    auto COMPUTE = [&](int buf) {
#pragma unroll
        for (int kk = 0; kk < 2; ++kk) {
            const int cl = kk * 2 + (lane >> 5);
            bf16x8 af[2], bfr[2];
#pragma unroll
            for (int mf = 0; mf < 2; ++mf) {
                const int r = wm * 64 + mf * 32 + (lane & 31);
                af[mf] = *(const bf16x8*)&As[buf][r * 32 + ((cl ^ (r & 3)) << 3)];
            }
#pragma unroll
            for (int nf = 0; nf < 2; ++nf) {
                const int r = wn * 64 + nf * 32 + (lane & 31);
                bfr[nf] = *(const bf16x8*)&Bs[buf][r * 32 + ((cl ^ (r & 3)) << 3)];
            }
#pragma unroll
            for (int mf = 0; mf < 2; ++mf)
#pragma unroll
                for (int nf = 0; nf < 2; ++nf)
                    acc[mf][nf] = __builtin_amdgcn_mfma_f32_32x32x16_bf16(
                        af[mf], bfr[nf], acc[mf][nf], 0, 0, 0);
        }
    };

    // prologue: A(0) -> LDS buf0; B(0) + A(1) in flight
    GLB_A(0);
    CVT_WRITE(0, 0);          // compiler waits A(0) regs
    GLB_B(0, 0);
    GLB_A(1);
    // main loop
    for (int t = 0; t < NT - 1; ++t) {
        const int buf = t & 1, nbuf = buf ^ 1;
        GLB_B(t + 1, nbuf);
        // queue: B(t)2 (oldest), A(t+1)2, B(t+1)2 -> vmcnt(2) lands B(t)+A(t+1)
        asm volatile("s_waitcnt vmcnt(2)" ::: "memory");
        CVT_WRITE(t + 1, nbuf);
        if (t + 2 < NT) GLB_A(t + 2);
        asm volatile("s_waitcnt lgkmcnt(0)" ::: "memory");   // ds_write visible
        __builtin_amdgcn_s_barrier();
        COMPUTE(buf);
        __builtin_amdgcn_s_barrier();    // protect As/Bs[nbuf... buf] overwrite
    }
    asm volatile("s_waitcnt vmcnt(0)" ::: "memory");
    __builtin_amdgcn_s_barrier();
    COMPUTE((NT - 1) & 1);

    // epilogue: bf16 partials; 32x32 C/D: col=lane&31, row=(r&3)+8*(r>>2)+4*(lane>>5)
    uint16_t* dst = parts + (size_t)ks * NN * FF;
    const int rb = m0 + wm * 64 + ((lane >> 5) << 2);
    const int cb = n0 + wn * 64 + (lane & 31);
#pragma unroll
    for (int mf = 0; mf < 2; ++mf)
#pragma unroll
        for (int nf = 0; nf < 2; ++nf) {
            const int gcol = cb + nf * 32;
#pragma unroll
            for (int r = 0; r < 16; ++r) {
                const int grow = rb + mf * 32 + (r & 3) + ((r >> 2) << 3);
                dst[(size_t)grow * FF + gcol] = f2bf(acc[mf][nf][r]);
            }
        }
}

// ---------------------------------------------------------------------------
// k_red: out[i][j] = d[i] * sum_{p=0..7} bf2f(parts[p][i][j]) + b[j]
// ---------------------------------------------------------------------------
__global__ __launch_bounds__(256) void k_red(const uint16_t* __restrict__ parts,
                                             const float* __restrict__ d,
                                             const float* __restrict__ b,
                                             float* __restrict__ out) {
    constexpr size_t STRIDE = (size_t)NN * FF;
    const size_t g   = (size_t)blockIdx.x * 256 + threadIdx.x;
    const int    row = (int)((g * 8) >> 9);
    const int    col = (int)((g * 8) & 511);
    float s[8] = {};
#pragma unroll
    for (int p = 0; p < 8; ++p) {
        ushort4 v0 = *(const ushort4*)(parts + p * STRIDE + g * 8);
        ushort4 v1 = *(const ushort4*)(parts + p * STRIDE + g * 8 + 4);
        s[0] += bf2f(v0.x); s[1] += bf2f(v0.y); s[2] += bf2f(v0.z); s[3] += bf2f(v0.w);
        s[4] += bf2f(v1.x); s[5] += bf2f(v1.y); s[6] += bf2f(v1.z); s[7] += bf2f(v1.w);
    }
    const float di = d[row];
    float4 o0, o1;
    o0.x = s[0] * di + b[col + 0];
    o0.y = s[1] * di + b[col + 1];
    o0.z = s[2] * di + b[col + 2];
    o0.w = s[3] * di + b[col + 3];
    o1.x = s[4] * di + b[col + 4];
    o1.y = s[5] * di + b[col + 5];
    o1.z = s[6] * di + b[col + 6];
    o1.w = s[7] * di + b[col + 7];
    *(float4*)(out + g * 8)     = o0;
    *(float4*)(out + g * 8 + 4) = o1;
}

// ---------------------------------------------------------------------------
extern "C" void kernel_launch(void* const* d_in, const int* in_sizes, int n_in,
                              void* d_out, int out_size, void* d_ws, size_t ws_size,
                              hipStream_t stream) {
    const float* x   = (const float*)d_in[0];   // [4096][512]
    const float* adj = (const float*)d_in[1];   // [4096][4096]
    const float* W   = (const float*)d_in[2];   // [512][512]
    const float* b   = (const float*)d_in[3];   // [512]
    float* out = (float*)d_out;                 // [4096][512] f32

    char* ws = (char*)d_ws;
    float*    d_    = (float*)ws;                                 // 16 KB (pad 64K)
    uint16_t* zdT   = (uint16_t*)(ws + 65536);                    // 4 MB
    uint16_t* xbf   = zdT + (size_t)FF * NN;                      // 4 MB
    uint16_t* Wbf   = xbf + (size_t)NN * FF;                      // 0.5 MB
    uint16_t* parts = Wbf + (size_t)FF * FF;                      // 32 MB (8 x 4MB bf16)

    k_wc<<<FF * FF / 1024, 256, 0, stream>>>(W, Wbf);
    k_xc<<<NN * FF / 1024, 256, 0, stream>>>(x, xbf);
    // d_i = rsqrt(1+rowsum); warms L3 with adj
    k_dsum<<<NN / 4, 256, 0, stream>>>(adj, d_);
    // zdT[n][k] = d_k * (x @ W^T)[k][n]
    k_mmz<<<512, 256, 0, stream>>>(xbf, Wbf, d_, zdT);
    // parts[ks] = (adj+I) @ zdT^T  (A direct from f32 adj, inline cvt+diag)
    k_mmx<<<512, 512, 0, stream>>>(adj, zdT, parts);
    // out = d[i] * sum_ks(parts) + b
    k_red<<<NN * FF / 2048, 256, 0, stream>>>(parts, d_, b, out);
}

// Round 14
// 57.706 us; speedup vs baseline: 1.7047x; 1.1981x over previous
//
#include <hip/hip_runtime.h>
#include <cstdint>

#define NN 4096
#define FF 512

typedef short bf16x8 __attribute__((ext_vector_type(8)));
typedef float f32x4 __attribute__((ext_vector_type(4)));
typedef float f32x16 __attribute__((ext_vector_type(16)));

__device__ __forceinline__ uint16_t f2bf(float f) {
    uint32_t u = __builtin_bit_cast(uint32_t, f);
    u += 0x7FFFu + ((u >> 16) & 1u);   // round-to-nearest-even
    return (uint16_t)(u >> 16);
}
__device__ __forceinline__ float bf2f(uint32_t h) {
    uint32_t u = h << 16;
    return __builtin_bit_cast(float, u);
}

// ---------------------------------------------------------------------------
// k_pre: fused preprocessing, one launch (saves 2 launch gaps).
//   blocks [0,1024):    prep — Abf[i][j]=bf16(adj+I), d_i=rsqrt(1+rowsum)
//   blocks [1024,3072): xc   — x f32 -> bf16
//   blocks [3072,3328): wc   — W f32 -> bf16
// ---------------------------------------------------------------------------
__global__ __launch_bounds__(256) void k_pre(const float* __restrict__ adj,
                                             const float* __restrict__ x,
                                             const float* __restrict__ W,
                                             float* __restrict__ d,
                                             uint16_t* __restrict__ Abf,
                                             uint16_t* __restrict__ xbf,
                                             uint16_t* __restrict__ Wbf) {
    const int bid = blockIdx.x;
    if (bid < 1024) {                       // ---- prep (R9-verified body) ----
        const int row  = bid * 4 + (threadIdx.x >> 6);
        const int lane = threadIdx.x & 63;
        const float4* p = (const float4*)(adj + (size_t)row * NN);
        float4 v[16];
        float s = 0.f;
#pragma unroll
        for (int i = 0; i < 16; ++i) {
            v[i] = p[lane + i * 64];
            s += (v[i].x + v[i].y) + (v[i].z + v[i].w);
        }
#pragma unroll
        for (int off = 1; off < 64; off <<= 1) s += __shfl_xor(s, off);
        const float di = rsqrtf(s + 1.0f);
        if (lane == 0) d[row] = di;
        uint16_t* outp = Abf + (size_t)row * NN;
#pragma unroll
        for (int i = 0; i < 16; ++i) {
            const int cb = (lane + i * 64) * 4;
            float a0 = v[i].x, a1 = v[i].y, a2 = v[i].z, a3 = v[i].w;
            if (cb + 0 == row) a0 += 1.0f;
            if (cb + 1 == row) a1 += 1.0f;
            if (cb + 2 == row) a2 += 1.0f;
            if (cb + 3 == row) a3 += 1.0f;
            ushort4 o;
            o.x = f2bf(a0); o.y = f2bf(a1); o.z = f2bf(a2); o.w = f2bf(a3);
            *(ushort4*)(outp + cb) = o;
        }
    } else if (bid < 3072) {                // ---- xc ----
        const size_t t4 = (size_t)(bid - 1024) * 256 + threadIdx.x;
        float4 v = *(const float4*)(x + t4 * 4);
        ushort4 o;
        o.x = f2bf(v.x); o.y = f2bf(v.y); o.z = f2bf(v.z); o.w = f2bf(v.w);
        *(ushort4*)(xbf + t4 * 4) = o;
    } else {                                // ---- wc ----
        const size_t t4 = (size_t)(bid - 3072) * 256 + threadIdx.x;
        float4 v = *(const float4*)(W + t4 * 4);
        ushort4 o;
        o.x = f2bf(v.x); o.y = f2bf(v.y); o.z = f2bf(v.z); o.w = f2bf(v.w);
        *(ushort4*)(Wbf + t4 * 4) = o;
    }
}

// ---------------------------------------------------------------------------
// k_mmz: fused small GEMM + transpose + d-scale (R12/R13-verified).
// zdT[n][k] = bf16( d[k] * (x @ W^T)[k][n] )
// ---------------------------------------------------------------------------
__global__ __launch_bounds__(256, 4) void k_mmz(const uint16_t* __restrict__ A,
                                                const uint16_t* __restrict__ Bt,
                                                const float* __restrict__ d,
                                                uint16_t* __restrict__ zdT) {
    constexpr int BM = 64, BN = 64, K = FF;
    constexpr int NTC = FF / BN;          // 8
    constexpr int NT  = K / 64;           // 8

    __shared__ uint16_t As[BM * 64];
    __shared__ uint16_t Bs[BN * 64];
    __shared__ uint16_t tt[64][80];

    const int id = blockIdx.x;
    const int mt = id / NTC;
    const int nt = id % NTC;
    const int m0 = mt * BM;
    const int n0 = nt * BN;

    const int tid  = threadIdx.x;
    const int w    = tid >> 6;
    const int lane = tid & 63;
    const int wm = w >> 1, wn = w & 1;

    f32x4 acc[2][2] = {};

    for (int t = 0; t < NT; ++t) {
        const int ktb = t * 64;
#pragma unroll
        for (int i = 0; i < 2; ++i) {
            const int boff = i * 4096 + tid * 16;
            const int row  = boff >> 7;
            const int q    = (boff >> 4) & 7;
            const int c    = q ^ (row & 7);
            const uint16_t* src = A + (size_t)(m0 + row) * K + ktb + c * 8;
            __builtin_amdgcn_global_load_lds(
                (const __attribute__((address_space(1))) void*)src,
                (__attribute__((address_space(3))) void*)&As[boff >> 1],
                16, 0, 0);
        }
#pragma unroll
        for (int i = 0; i < 2; ++i) {
            const int boff = i * 4096 + tid * 16;
            const int row  = boff >> 7;
            const int q    = (boff >> 4) & 7;
            const int c    = q ^ (row & 7);
            const uint16_t* src = Bt + (size_t)(n0 + row) * K + ktb + c * 8;
            __builtin_amdgcn_global_load_lds(
                (const __attribute__((address_space(1))) void*)src,
                (__attribute__((address_space(3))) void*)&Bs[boff >> 1],
                16, 0, 0);
        }
        __syncthreads();
#pragma unroll
        for (int kk = 0; kk < 2; ++kk) {
            const int cl = kk * 4 + (lane >> 4);
            bf16x8 af[2], bfr[2];
#pragma unroll
            for (int mf = 0; mf < 2; ++mf) {
                const int r = wm * 32 + mf * 16 + (lane & 15);
                af[mf] = *(const bf16x8*)&As[r * 64 + ((cl ^ (r & 7)) << 3)];
            }
#pragma unroll
            for (int nf = 0; nf < 2; ++nf) {
                const int r = wn * 32 + nf * 16 + (lane & 15);
                bfr[nf] = *(const bf16x8*)&Bs[r * 64 + ((cl ^ (r & 7)) << 3)];
            }
#pragma unroll
            for (int mf = 0; mf < 2; ++mf)
#pragma unroll
                for (int nf = 0; nf < 2; ++nf)
                    acc[mf][nf] = __builtin_amdgcn_mfma_f32_16x16x32_bf16(
                        af[mf], bfr[nf], acc[mf][nf], 0, 0, 0);
        }
        __syncthreads();
    }

    const int rb = wm * 32 + ((lane >> 4) << 2);
    const int cb = wn * 32 + (lane & 15);
#pragma unroll
    for (int mf = 0; mf < 2; ++mf)
#pragma unroll
        for (int nf = 0; nf < 2; ++nf) {
            const int col_l = cb + nf * 16;
#pragma unroll
            for (int r = 0; r < 4; ++r) {
                const int row_l = rb + mf * 16 + r;
                tt[col_l][row_l] = f2bf(acc[mf][nf][r] * d[m0 + row_l]);
            }
        }
    __syncthreads();
    const int n_l = tid >> 2;
    const int ch  = tid & 3;
    uint4* dst = (uint4*)(zdT + (size_t)(n0 + n_l) * NN + m0 + ch * 16);
    dst[0] = *(const uint4*)&tt[n_l][ch * 16];
    dst[1] = *(const uint4*)&tt[n_l][ch * 16 + 8];
}

// ---------------------------------------------------------------------------
// k_mmx: R9-verbatim big GEMM (measured 29.6 µs via R10 double-launch delta).
// parts[ks] = Abf @ zdT^T k-slice. BM=BN=128, BK=64, 256 thr (4 waves 2x2),
// wave tile 64x64 = 2x2 of 32x32x16 frags. Ring-2 LDS, counted vmcnt(8).
// 8-slot XOR chunk swizzle. Split-K=4, bf16 partials row-major.
// ---------------------------------------------------------------------------
__global__ __launch_bounds__(256, 2) void k_mmx(const uint16_t* __restrict__ A,
                                                const uint16_t* __restrict__ Bt,
                                                uint16_t* __restrict__ parts) {
    constexpr int BM = 128, BN = 128, K = NN, SPLITK = 4;
    constexpr int NTC   = FF / BN;        // 4
    constexpr int KSLEN = K / SPLITK;     // 1024
    constexpr int NT    = KSLEN / 64;     // 16
    constexpr int MTX   = (NN / BM) / 8;  // 4

    __shared__ uint16_t As[2][BM * 64];
    __shared__ uint16_t Bs[2][BN * 64];

    const int id   = blockIdx.x;          // 0..511
    const int xcd  = id & 7;
    const int slot = id >> 3;             // 0..63
    const int mt   = xcd * MTX + slot / (NTC * SPLITK);
    const int rem  = slot % (NTC * SPLITK);
    const int nt   = rem % NTC;
    const int ks   = rem / NTC;
    const int m0 = mt * BM;
    const int n0 = nt * BN;
    const int k0 = ks * KSLEN;

    const int tid  = threadIdx.x;
    const int w    = tid >> 6;
    const int lane = tid & 63;
    const int wm = w >> 1, wn = w & 1;

    f32x16 acc[2][2] = {};

    auto STAGE = [&](int t, int buf) {
        const int ktb = k0 + t * 64;
#pragma unroll
        for (int i = 0; i < 4; ++i) {
            const int boff = i * 4096 + tid * 16;
            const int row  = boff >> 7;
            const int q    = (boff >> 4) & 7;
            const int c    = q ^ (row & 7);
            const uint16_t* src = A + (size_t)(m0 + row) * K + ktb + c * 8;
            __builtin_amdgcn_global_load_lds(
                (const __attribute__((address_space(1))) void*)src,
                (__attribute__((address_space(3))) void*)&As[buf][boff >> 1],
                16, 0, 0);
        }
#pragma unroll
        for (int i = 0; i < 4; ++i) {
            const int boff = i * 4096 + tid * 16;
            const int row  = boff >> 7;
            const int q    = (boff >> 4) & 7;
            const int c    = q ^ (row & 7);
            const uint16_t* src = Bt + (size_t)(n0 + row) * K + ktb + c * 8;
            __builtin_amdgcn_global_load_lds(
                (const __attribute__((address_space(1))) void*)src,
                (__attribute__((address_space(3))) void*)&Bs[buf][boff >> 1],
                16, 0, 0);
        }
    };

    auto COMPUTE = [&](int buf) {
#pragma unroll
        for (int kk = 0; kk < 4; ++kk) {
            const int cl = kk * 2 + (lane >> 5);
            bf16x8 af[2], bfr[2];
#pragma unroll
            for (int mf = 0; mf < 2; ++mf) {
                const int r = wm * 64 + mf * 32 + (lane & 31);
                af[mf] = *(const bf16x8*)&As[buf][r * 64 + ((cl ^ (r & 7)) << 3)];
            }
#pragma unroll
            for (int nf = 0; nf < 2; ++nf) {
                const int r = wn * 64 + nf * 32 + (lane & 31);
                bfr[nf] = *(const bf16x8*)&Bs[buf][r * 64 + ((cl ^ (r & 7)) << 3)];
            }
#pragma unroll
            for (int mf = 0; mf < 2; ++mf)
#pragma unroll
                for (int nf = 0; nf < 2; ++nf)
                    acc[mf][nf] = __builtin_amdgcn_mfma_f32_32x32x16_bf16(
                        af[mf], bfr[nf], acc[mf][nf], 0, 0, 0);
        }
    };

    STAGE(0, 0);
    for (int t = 0; t < NT - 1; ++t) {
        STAGE(t + 1, (t + 1) & 1);
        asm volatile("s_waitcnt vmcnt(8)" ::: "memory");
        __builtin_amdgcn_s_barrier();
        COMPUTE(t & 1);
        __builtin_amdgcn_s_barrier();
    }
    asm volatile("s_waitcnt vmcnt(0)" ::: "memory");
    __builtin_amdgcn_s_barrier();
    COMPUTE((NT - 1) & 1);

    uint16_t* dst = parts + (size_t)ks * NN * FF;
    const int rb = m0 + wm * 64 + ((lane >> 5) << 2);
    const int cb = n0 + wn * 64 + (lane & 31);
#pragma unroll
    for (int mf = 0; mf < 2; ++mf)
#pragma unroll
        for (int nf = 0; nf < 2; ++nf) {
            const int gcol = cb + nf * 32;
#pragma unroll
            for (int r = 0; r < 16; ++r) {
                const int grow = rb + mf * 32 + (r & 3) + ((r >> 2) << 3);
                dst[(size_t)grow * FF + gcol] = f2bf(acc[mf][nf][r]);
            }
        }
}

// ---------------------------------------------------------------------------
// k_red: out[i][j] = d[i] * sum_{p=0..3} bf2f(parts[p][i][j]) + b[j]
// ---------------------------------------------------------------------------
__global__ __launch_bounds__(256) void k_red(const uint16_t* __restrict__ parts,
                                             const float* __restrict__ d,
                                             const float* __restrict__ b,
                                             float* __restrict__ out) {
    constexpr size_t STRIDE = (size_t)NN * FF;
    const size_t g   = (size_t)blockIdx.x * 256 + threadIdx.x;
    const int    row = (int)((g * 8) >> 9);
    const int    col = (int)((g * 8) & 511);
    float s[8] = {};
#pragma unroll
    for (int p = 0; p < 4; ++p) {
        ushort4 v0 = *(const ushort4*)(parts + p * STRIDE + g * 8);
        ushort4 v1 = *(const ushort4*)(parts + p * STRIDE + g * 8 + 4);
        s[0] += bf2f(v0.x); s[1] += bf2f(v0.y); s[2] += bf2f(v0.z); s[3] += bf2f(v0.w);
        s[4] += bf2f(v1.x); s[5] += bf2f(v1.y); s[6] += bf2f(v1.z); s[7] += bf2f(v1.w);
    }
    const float di = d[row];
    float4 o0, o1;
    o0.x = s[0] * di + b[col + 0];
    o0.y = s[1] * di + b[col + 1];
    o0.z = s[2] * di + b[col + 2];
    o0.w = s[3] * di + b[col + 3];
    o1.x = s[4] * di + b[col + 4];
    o1.y = s[5] * di + b[col + 5];
    o1.z = s[6] * di + b[col + 6];
    o1.w = s[7] * di + b[col + 7];
    *(float4*)(out + g * 8)     = o0;
    *(float4*)(out + g * 8 + 4) = o1;
}

// ---------------------------------------------------------------------------
extern "C" void kernel_launch(void* const* d_in, const int* in_sizes, int n_in,
                              void* d_out, int out_size, void* d_ws, size_t ws_size,
                              hipStream_t stream) {
    const float* x   = (const float*)d_in[0];   // [4096][512]
    const float* adj = (const float*)d_in[1];   // [4096][4096]
    const float* W   = (const float*)d_in[2];   // [512][512]
    const float* b   = (const float*)d_in[3];   // [512]
    float* out = (float*)d_out;                 // [4096][512] f32

    char* ws = (char*)d_ws;
    float*    d_    = (float*)ws;                                 // 16 KB (pad 64K)
    uint16_t* Abf   = (uint16_t*)(ws + 65536);                    // 32 MB
    uint16_t* zdT   = Abf + (size_t)NN * NN;                      // 4 MB
    uint16_t* xbf   = zdT + (size_t)FF * NN;                      // 4 MB
    uint16_t* Wbf   = xbf + (size_t)NN * FF;                      // 0.5 MB
    uint16_t* parts = Wbf + (size_t)FF * FF;                      // 16 MB (4 x 4MB bf16)

    // one fused preprocessing launch: prep (1024) + xc (2048) + wc (256)
    k_pre<<<3328, 256, 0, stream>>>(adj, x, W, d_, Abf, xbf, Wbf);
    // zdT[n][k] = d_k * (x @ W^T)[k][n]
    k_mmz<<<512, 256, 0, stream>>>(xbf, Wbf, d_, zdT);
    // parts[ks] = Abf @ zdT^T k-slice (R9-verbatim core)
    k_mmx<<<512, 256, 0, stream>>>(Abf, zdT, parts);
    // out = d[i] * sum_ks(parts) + b
    k_red<<<NN * FF / 2048, 256, 0, stream>>>(parts, d_, b, out);
}